// Round 1
// 344.743 us; speedup vs baseline: 1.0210x; 1.0210x over previous
//
#include <hip/hip_runtime.h>
#include <hip/hip_fp16.h>

#define D 128
#define NB_MAX 1024
#define PART_BLOCKS 512
#define CNT_BLOCKS 512

using f32x4  = __attribute__((ext_vector_type(4))) float;
using half8  = __attribute__((ext_vector_type(8))) _Float16;
using short8 = __attribute__((ext_vector_type(8))) short;

#define AS1(p) ((const __attribute__((address_space(1))) void*)(p))
#define AS3(p) ((__attribute__((address_space(3))) void*)(p))

// v_fma_mix_f32: acc += (float)(f16 half of dw) * 1.0f  — one VALU op replaces cvt+fma
#define FMA_MIX_LO(acc, dw, one) \
    asm("v_fma_mix_f32 %0, %1, %2, %0 op_sel:[0,0,0] op_sel_hi:[1,0,0]" \
        : "+v"(acc) : "v"(dw), "v"(one))
#define FMA_MIX_HI(acc, dw, one) \
    asm("v_fma_mix_f32 %0, %1, %2, %0 op_sel:[1,0,0] op_sel_hi:[1,0,0]" \
        : "+v"(acc) : "v"(dw), "v"(one))

// ------------------------------------------------ fused prep + bucket count:
//  blocks [0, CNT_BLOCKS)       : bucket histogram of dst (runs concurrent with rest)
//  blocks [CNT, CNT+256)        : W1/W2 -> f16 hi/lo planes (k-major swizzle)
//  blocks [CNT+256, ...)        : x fp32 -> fp16
// Wg layout: (((kc*2 + plane)*4 + q)*128 + col)*8 + j ; k = kc*32+q*8+j
__global__ void prep_k(const float* __restrict__ x, __half* __restrict__ y, int n4,
                       const float* __restrict__ W1s, const float* __restrict__ W1n,
                       const float* __restrict__ W2s, const float* __restrict__ W2n,
                       unsigned short* __restrict__ Wg1, unsigned short* __restrict__ Wg2,
                       const int* __restrict__ dst, int* __restrict__ bucket_counts,
                       int E, int nb, float* __restrict__ xpad) {
    __shared__ int hist[NB_MAX];
    int b = blockIdx.x;
    int t = threadIdx.x;
    if (b < CNT_BLOCKS) {          // bucket counting (scheduled first -> overlaps)
        if (b == 0 && t < 64) xpad[t] = 0.f;   // zero-row pad for aggregate tail
        for (int i = t; i < nb; i += 256) hist[i] = 0;
        __syncthreads();
        for (int i = b * 256 + t; i < E; i += CNT_BLOCKS * 256)
            atomicAdd(&hist[dst[i] >> 8], 1);
        __syncthreads();
        for (int i = t; i < nb; i += 256) {
            int c = hist[i];
            if (c) atomicAdd(&bucket_counts[i], c);
        }
        return;
    }
    int wb = b - CNT_BLOCKS;
    if (wb < 256) {                // weight hi/lo split
        int sel = wb >> 7;         // 0: W1, 1: W2
        int lb  = wb & 127;
        const float* Ws = sel ? W2s : W1s;
        const float* Wn = sel ? W2n : W1n;
        unsigned short* Wg = sel ? Wg2 : Wg1;
        int idx = lb * 256 + t;    // 0 .. 32767
        int col = idx >> 8;
        int k   = idx & 255;
        float v = (k < 128) ? Ws[k * D + col] : Wn[(k - 128) * D + col];
        _Float16 hv = (_Float16)v;
        _Float16 lv = (_Float16)(v - (float)hv);
        int kc = k >> 5, q = (k >> 3) & 3, j = k & 7;
        Wg[(((kc * 2 + 0) * 4 + q) * 128 + col) * 8 + j] = *(unsigned short*)&hv;
        Wg[(((kc * 2 + 1) * 4 + q) * 128 + col) * 8 + j] = *(unsigned short*)&lv;
        return;
    }
    int i = (b - CNT_BLOCKS - 256) * 256 + t;
    if (i < n4) {
        float4 v = *(const float4*)(x + (size_t)i * 4);
        __half2 h0 = __floats2half2_rn(v.x, v.y);
        __half2 h1 = __floats2half2_rn(v.z, v.w);
        __half2* o = (__half2*)(y + (size_t)i * 4);
        o[0] = h0; o[1] = h1;
    }
}

// ------------------------------------------------ CSR build, bucketed (256 nodes/bucket)
__global__ void bucket_scan_k(const int* __restrict__ bucket_counts,
                              int* __restrict__ bucket_base,
                              int* __restrict__ bucket_cursor, int nb) {
    __shared__ int sh[256];
    int t = threadIdx.x;
    int base = t * 4;
    int v0 = (base + 0 < nb) ? bucket_counts[base + 0] : 0;
    int v1 = (base + 1 < nb) ? bucket_counts[base + 1] : 0;
    int v2 = (base + 2 < nb) ? bucket_counts[base + 2] : 0;
    int v3 = (base + 3 < nb) ? bucket_counts[base + 3] : 0;
    int tsum = v0 + v1 + v2 + v3;
    sh[t] = tsum;
    __syncthreads();
    for (int off = 1; off < 256; off <<= 1) {
        int x = 0;
        if (t >= off) x = sh[t - off];
        __syncthreads();
        if (t >= off) sh[t] += x;
        __syncthreads();
    }
    int excl = sh[t] - tsum;
    if (base + 0 < nb) { bucket_base[base+0] = excl;          bucket_cursor[base+0] = excl; }
    if (base + 1 < nb) { bucket_base[base+1] = excl+v0;       bucket_cursor[base+1] = excl+v0; }
    if (base + 2 < nb) { bucket_base[base+2] = excl+v0+v1;    bucket_cursor[base+2] = excl+v0+v1; }
    if (base + 3 < nb) { bucket_base[base+3] = excl+v0+v1+v2; bucket_cursor[base+3] = excl+v0+v1+v2; }
    if (t == 255) bucket_base[nb] = sh[255];
}

__global__ void partition_k(const int* __restrict__ src, const int* __restrict__ dst,
                            int* __restrict__ bucket_cursor, unsigned* __restrict__ pairs,
                            int E, int nb, int chunk) {
    __shared__ int hist[NB_MAX];
    __shared__ int bbase[NB_MAX];
    int t = threadIdx.x;
    int e0 = blockIdx.x * chunk;
    int e1 = min(E, e0 + chunk);
    for (int b = t; b < nb; b += 256) hist[b] = 0;
    __syncthreads();
    for (int i = e0 + t; i < e1; i += 256)
        atomicAdd(&hist[dst[i] >> 8], 1);
    __syncthreads();
    for (int b = t; b < nb; b += 256) {
        int c = hist[b];
        int bs = 0;
        if (c) bs = atomicAdd(&bucket_cursor[b], c);
        bbase[b] = bs;
        hist[b] = 0;            // reuse as local cursor
    }
    __syncthreads();
    for (int i = e0 + t; i < e1; i += 256) {
        int dd = dst[i];
        int b = dd >> 8;
        int r = atomicAdd(&hist[b], 1);
        pairs[bbase[b] + r] = ((unsigned)(dd & 255) << 17) | (unsigned)src[i];
    }
}

__global__ void build_csr_k(const unsigned* __restrict__ pairs,
                            const int* __restrict__ bucket_base,
                            int2* __restrict__ offcnt,
                            int* __restrict__ edge_src, int N) {
    __shared__ int hist[256];
    __shared__ int curs[256];
    __shared__ int sh[256];
    int t = threadIdx.x;
    int b = blockIdx.x;
    int n0 = b << 8;
    int e0 = bucket_base[b];
    int e1 = bucket_base[b + 1];
    hist[t] = 0;
    __syncthreads();
    for (int i = e0 + t; i < e1; i += 256)
        atomicAdd(&hist[pairs[i] >> 17], 1);
    __syncthreads();
    int c = hist[t];
    sh[t] = c;
    __syncthreads();
    for (int off = 1; off < 256; off <<= 1) {
        int x = 0;
        if (t >= off) x = sh[t - off];
        __syncthreads();
        if (t >= off) sh[t] += x;
        __syncthreads();
    }
    int excl = sh[t] - c;
    curs[t] = excl;
    int node = n0 + t;
    if (node < N) offcnt[node] = make_int2(e0 + excl, c);
    __syncthreads();
    for (int i = e0 + t; i < e1; i += 256) {
        unsigned p = pairs[i];
        int pos = atomicAdd(&curs[p >> 17], 1);
        edge_src[e0 + pos] = (int)(p & 0x1FFFFu);
    }
}

// ------------------------------------------------ neighbor mean, fp16 in/out
// one wave per dst node; 16 lanes x 16B per row; 16 edges per inner iter
// (4 batched loads per lane -> 4x memory-level parallelism).
// invalid lanes gather the all-zero pad row (index n) -> no tail mask math;
// accumulation via v_fma_mix_f32 (f16 src, f32 acc) -> 1 VALU op per element.
__global__ void aggregate_f16_k(const __half* __restrict__ x,
                                const int* __restrict__ edge_src,
                                const int2* __restrict__ offcnt,
                                __half* __restrict__ agg, int n) {
    int wid  = (blockIdx.x * blockDim.x + threadIdx.x) >> 6;
    int lane = threadIdx.x & 63;
    if (wid >= n) return;
    int sg  = lane >> 4;     // 0..3: edge slot within each group of 4
    int sub = lane & 15;     // 16 lanes cover one 256B row
    int2 oc = offcnt[wid];
    int start = oc.x;
    int cnt   = oc.y;
    float one = 1.0f;
    float acc[8] = {0.f, 0.f, 0.f, 0.f, 0.f, 0.f, 0.f, 0.f};
    for (int base = 0; base < cnt; base += 64) {
        int valid = min(64, cnt - base);
        int s = (lane < valid) ? edge_src[start + base + lane] : n;  // n = zero row
        for (int k0 = 0; k0 < valid; k0 += 16) {
            float4 raw[4];
            #pragma unroll
            for (int u = 0; u < 4; ++u) {
                int row = __shfl(s, (k0 + 4 * u + sg) & 63);
                raw[u] = *(const float4*)(x + (size_t)row * D + sub * 8);
            }
            #pragma unroll
            for (int u = 0; u < 4; ++u) {
                const unsigned* dw = (const unsigned*)&raw[u];
                #pragma unroll
                for (int j = 0; j < 4; ++j) {
                    FMA_MIX_LO(acc[2 * j],     dw[j], one);
                    FMA_MIX_HI(acc[2 * j + 1], dw[j], one);
                }
            }
        }
    }
    #pragma unroll
    for (int j = 0; j < 8; ++j) {
        acc[j] += __shfl(acc[j], lane ^ 16);
        acc[j] += __shfl(acc[j], lane ^ 32);
    }
    if (sg == 0) {
        float inv = 1.0f / fmaxf((float)cnt, 1.0f);
        union { __half2 h2[4]; short8 s8; } u;
        #pragma unroll
        for (int j = 0; j < 4; ++j)
            u.h2[j] = __floats2half2_rn(acc[2 * j] * inv, acc[2 * j + 1] * inv);
        *(short8*)(agg + (size_t)wid * D + sub * 8) = u.s8;
    }
}

// ------------------------------------------------ fp16 2-term MFMA GEMM, LDS-staged B
// C = A0 @ W[:128] + A1 @ W[128:] + b  with W = Whi + Wlo (f16 split)
// block = 512 thr = 8 waves = 256 rows sharing each 16KB B-stage (halves
// B L2 refetch + barriers per row vs 128-row blocks).
__global__ __launch_bounds__(512)
void mfma_gemm_k(const _Float16* __restrict__ A0, const _Float16* __restrict__ A1,
                 const unsigned short* __restrict__ Wg,
                 const float* __restrict__ bias,
                 float* __restrict__ C, __half* __restrict__ Ch,
                 int n, int out_mode) {
    __shared__ __align__(16) unsigned short lds_b[8192];   // 16 KB
    int t = threadIdx.x;
    int w = t >> 6;
    int l = t & 63;
    int m = l & 15;          // A row within tile / B,C col within tile
    int q = l >> 4;          // quad
    int r0 = blockIdx.x * 256 + w * 32;

    f32x4 acc[2][8];
    #pragma unroll
    for (int rt = 0; rt < 2; ++rt)
        #pragma unroll
        for (int ct = 0; ct < 8; ++ct)
            acc[rt][ct] = (f32x4){0.f, 0.f, 0.f, 0.f};

    for (int kc = 0; kc < 8; ++kc) {
        // async stage B chunk (16 KB contiguous) into LDS: 1024 x 16B, 2/thread
        const unsigned short* gk = Wg + (size_t)kc * 8192;
        #pragma unroll
        for (int i = 0; i < 2; ++i) {
            int e = i * 512 + t;
            __builtin_amdgcn_global_load_lds(AS1(gk + e * 8), AS3(lds_b + e * 8), 16, 0, 0);
        }
        // A fragments (fp16, 16B each) straight from global
        const _Float16* __restrict__ A = (kc < 4) ? A0 : A1;
        int ka = (kc & 3) * 32;
        half8 a[2];
        #pragma unroll
        for (int rt = 0; rt < 2; ++rt) {
            int row = r0 + rt * 16 + m;
            half8 v = (half8){0, 0, 0, 0, 0, 0, 0, 0};
            if (row < n) v = *(const half8*)(A + (size_t)row * D + ka + q * 8);
            a[rt] = v;
        }
        __syncthreads();     // drains global_load_lds + barrier

        #pragma unroll
        for (int ct = 0; ct < 8; ++ct) {
            half8 bh = *(const half8*)&lds_b[(size_t)(q * 128 + ct * 16 + m) * 8];
            half8 bl = *(const half8*)&lds_b[(size_t)((4 + q) * 128 + ct * 16 + m) * 8];
            #pragma unroll
            for (int rt = 0; rt < 2; ++rt) {
                acc[rt][ct] = __builtin_amdgcn_mfma_f32_16x16x32_f16(a[rt], bh, acc[rt][ct], 0, 0, 0);
                acc[rt][ct] = __builtin_amdgcn_mfma_f32_16x16x32_f16(a[rt], bl, acc[rt][ct], 0, 0, 0);
            }
        }
        __syncthreads();     // LDS reads done before next stage overwrites
    }

    #pragma unroll
    for (int ct = 0; ct < 8; ++ct) {
        int col = ct * 16 + m;
        float bb = bias[col];
        #pragma unroll
        for (int rt = 0; rt < 2; ++rt) {
            #pragma unroll
            for (int r = 0; r < 4; ++r) {
                int row = r0 + rt * 16 + q * 4 + r;
                if (row < n) {
                    float v = acc[rt][ct][r] + bb;
                    if (out_mode) {
                        v = fmaxf(v, 0.f);
                        Ch[(size_t)row * D + col] = __float2half(v);
                    } else {
                        C[(size_t)row * D + col] = v;
                    }
                }
            }
        }
    }
}

// ------------------------------------------------------------------- launch
extern "C" void kernel_launch(void* const* d_in, const int* in_sizes, int n_in,
                              void* d_out, int out_size, void* d_ws, size_t ws_size,
                              hipStream_t stream) {
    const float* in_feat = (const float*)d_in[0];
    const float* W1s     = (const float*)d_in[1];
    const float* W1n     = (const float*)d_in[2];
    const float* b1      = (const float*)d_in[3];
    const float* W2s     = (const float*)d_in[4];
    const float* W2n     = (const float*)d_in[5];
    const float* b2      = (const float*)d_in[6];
    const int*   src     = (const int*)d_in[7];
    const int*   dst     = (const int*)d_in[8];

    const int N  = in_sizes[0] / D;
    const int E  = in_sizes[7];
    const int NB = (N + 255) >> 8;     // 256-node buckets

    // workspace layout
    char* base = (char*)d_ws;
    size_t off = 0;
    __half* agg16 = (__half*)(base + off); off += (size_t)N * D * 2;        // neighbor means
    __half* xh16  = (__half*)(base + off); off += ((size_t)N * D + D) * 2;  // x16 (+1 zero row), then h16 in-place
    int* edge_src = (int*)(base + off);    off += (size_t)E * 4;
    int2* offcnt  = (int2*)(base + off);   off += (size_t)N * 8;
    unsigned short* Wg1 = (unsigned short*)(base + off); off += 65536 * 2;
    unsigned short* Wg2 = (unsigned short*)(base + off); off += 65536 * 2;
    int* bucket_counts = (int*)(base + off); off += NB_MAX * 4;
    int* bucket_base   = (int*)(base + off); off += (NB_MAX + 1) * 4;
    off = (off + 15) & ~(size_t)15;
    int* bucket_cursor = (int*)(base + off); off += NB_MAX * 4;

    unsigned* pairs = (unsigned*)agg16;  // aliases agg16 (consumed before agg16 written)
    float* xpad = (float*)(xh16 + (size_t)N * D);   // 256B zero row at index N

    const int chunk = (E + PART_BLOCKS - 1) / PART_BLOCKS;
    const int n4 = (N * D) / 4;
    const int xb = (n4 + 255) / 256;

    hipMemsetAsync(bucket_counts, 0, NB_MAX * 4, stream);

    // fused prep: bucket count (first, overlaps), W1/W2 hi-lo split, x->fp16, zero pad row
    hipLaunchKernelGGL(prep_k, dim3(CNT_BLOCKS + 256 + xb), dim3(256), 0, stream,
                       in_feat, xh16, n4, W1s, W1n, W2s, W2n, Wg1, Wg2,
                       dst, bucket_counts, E, NB, xpad);

    // CSR build (bucketed counting sort by dst)
    hipLaunchKernelGGL(bucket_scan_k, dim3(1), dim3(256), 0, stream,
                       bucket_counts, bucket_base, bucket_cursor, NB);
    hipLaunchKernelGGL(partition_k, dim3(PART_BLOCKS), dim3(256), 0, stream,
                       src, dst, bucket_cursor, pairs, E, NB, chunk);
    hipLaunchKernelGGL(build_csr_k, dim3(NB), dim3(256), 0, stream,
                       pairs, bucket_base, offcnt, edge_src, N);

    const dim3 aggGrid(((size_t)N * 64 + 255) / 256);
    const dim3 gemmGrid((N + 255) / 256);

    // layer 1: agg(x16) -> gemm -> h16 (in-place into xh16; fp32 h never materialized)
    hipLaunchKernelGGL(aggregate_f16_k, aggGrid, dim3(256), 0, stream,
                       xh16, edge_src, offcnt, agg16, N);
    hipLaunchKernelGGL(mfma_gemm_k, gemmGrid, dim3(512), 0, stream,
                       (const _Float16*)xh16, (const _Float16*)agg16, Wg1, b1,
                       (float*)nullptr, xh16, N, 1);

    // layer 2: agg(h16) -> gemm -> d_out fp32
    hipLaunchKernelGGL(aggregate_f16_k, aggGrid, dim3(256), 0, stream,
                       xh16, edge_src, offcnt, agg16, N);
    hipLaunchKernelGGL(mfma_gemm_k, gemmGrid, dim3(512), 0, stream,
                       (const _Float16*)xh16, (const _Float16*)agg16, Wg2, b2,
                       (float*)d_out, (__half*)nullptr, N, 0);
}